// Round 11
// baseline (33.659 us; speedup 1.0000x reference)
//
#include <hip/hip_runtime.h>
#include <hip/hip_bf16.h>

#define MM 512
#define LL 31
#define LDB 15
#define NPIX (MM*MM)
#define NOUT (NPIX*LDB)

#define NBLK1 (NPIX/512)      // 512 pass1 blocks (256 thr, 2 px/thread)
#define NPART (NBLK1*4)       // per-wave partials: 2048 floats
#define NBLK2 (NPIX/256)      // 1024 pass2 blocks
#define HTILE_V4 (256*LDB/4)  // 960 (pass2 tile)

typedef float f32x4 __attribute__((ext_vector_type(4)));   // native vec for nt-store

// ---- compile-time resize weight table (jax.image.resize linear, antialias) ----
struct WTab { float w[LDB][5]; int i0[LDB]; };

constexpr WTab make_wtab() {
    WTab t{};
    const double inv_scale = 31.0 / 15.0;
    const double ks = inv_scale;
    for (int k = 0; k < LDB; ++k) {
        double sf = (k + 0.5) * inv_scale - 0.5;
        double wv[LL] = {};
        double wsum = 0.0;
        for (int i = 0; i < LL; ++i) {
            double d = sf - (double)i;
            if (d < 0) d = -d;
            double w = 1.0 - d / ks;
            if (w < 0) w = 0;
            wv[i] = w;
            wsum += w;
        }
        int first = 0;
        while (first < LL && wv[first] == 0.0) ++first;
        t.i0[k] = first;
        for (int j = 0; j < 5; ++j) {
            int i = first + j;
            t.w[k][j] = (i < LL) ? (float)(wv[i] / wsum) : 0.0f;
        }
    }
    return t;
}

__constant__ WTab c_wtab = make_wtab();

__device__ __forceinline__ unsigned int enc_f32(float f) {
    unsigned int b = __float_as_uint(f);
    return (b & 0x80000000u) ? ~b : (b | 0x80000000u);
}
__device__ __forceinline__ float dec_f32(unsigned int u) {
    unsigned int b = (u & 0x80000000u) ? (u & 0x7fffffffu) : ~u;
    return __uint_as_float(b);
}

// ---- pass 1: 2 pixels/thread, all loads float2 (8B-aligned), no LDS/barriers ----
__global__ __launch_bounds__(256) void pass1_reg2_k(const float* __restrict__ X,
                                                    const float* __restrict__ y,
                                                    const float* __restrict__ H,
                                                    float* __restrict__ r_out,
                                                    float* __restrict__ partials) {
    const int tid  = threadIdx.x;
    const int bid  = blockIdx.x;
    const int lane = tid & 63;
    const int gid  = bid * 256 + tid;      // pixel-pair index; grid exact: 512*256*2 = NPIX
    const int p0   = gid * 2;

    // ---- load both X rows as 31 float2 (base byte = gid*248, 8B-aligned) ----
    const float2* x2 = (const float2*)(X + (size_t)p0 * LL);
    float xv[2 * LL];
#pragma unroll
    for (int i = 0; i < LL; ++i) {
        float2 v = x2[i];
        xv[2 * i]     = v.x;
        xv[2 * i + 1] = v.y;
    }

    // ---- load both H rows as 15 float2 (base byte = gid*120, 8B-aligned) ----
    const float2* h2 = (const float2*)(H + (size_t)p0 * LDB);
    float hv[2 * LDB];
#pragma unroll
    for (int k = 0; k < LDB; ++k) {
        float2 v = h2[k];
        hv[2 * k]     = v.x;
        hv[2 * k + 1] = v.y;
    }

    float2 yv = ((const float2*)y)[gid];   // coalesced

    // ---- per-pixel compute (q = 0,1), weights constant-folded from c_wtab ----
    float r01[2];
    float m = -1e30f;
#pragma unroll
    for (int q = 0; q < 2; ++q) {
        const float* xr_row = xv + q * LL;
        const float* h_row  = hv + q * LDB;
        float s = 0.f, hmin = 1e30f, hmax = -1e30f;
#pragma unroll
        for (int k = 0; k < LDB; ++k) {
            int i0 = c_wtab.i0[k];
            float xr = 0.f;
#pragma unroll
            for (int j = 0; j < 5; ++j) {
                int i = i0 + j;
                if (i > LL - 1) i = LL - 1;   // weight 0 there; clamp keeps index in-bounds
                xr += c_wtab.w[k][j] * xr_row[i];
            }
            float h = h_row[k];
            s += h * xr;
            hmin = fminf(hmin, h);
            hmax = fmaxf(hmax, h);
        }
        float r = s - ((q == 0) ? yv.x : yv.y);
        r01[q] = r;
        float mq = (r > 0.f) ? r * hmax : r * hmin;   // per-pixel max of H*r (H >= 0)
        m = fmaxf(m, mq);
    }

    ((float2*)r_out)[gid] = make_float2(r01[0], r01[1]);   // coalesced float2 store

    // wave64 butterfly max over both pixels
#pragma unroll
    for (int off = 32; off; off >>= 1) m = fmaxf(m, __shfl_xor(m, off));
    if (lane == 0) partials[bid * 4 + (tid >> 6)] = m;     // per-wave partial
}

// ---- pass 2: overlapped partials-reduce + out = H * r / max (1 barrier) ----
__global__ __launch_bounds__(256) void pass2_k(const float4* __restrict__ H4,
                                               const float* __restrict__ r_in,
                                               const float* __restrict__ partials,
                                               f32x4* __restrict__ out4) {
    __shared__ float lds_r[256];
    __shared__ float redbuf[4];

    const int tid  = threadIdx.x;
    const int bid  = blockIdx.x;
    const int wv   = tid >> 6;
    const int lane = tid & 63;

    // issue ALL loads up front so they overlap the reduce
    const float4* p4 = (const float4*)partials;        // NPART/4 = 512 float4
    float4 a0 = p4[wv * 128 + lane];
    float4 a1 = p4[wv * 128 + 64 + lane];

    const float4* Ht = H4 + (size_t)bid * HTILE_V4;
    float4 h0 = Ht[tid];
    float4 h1 = Ht[256 + tid];
    float4 h2 = Ht[512 + tid];
    const bool has3 = tid < HTILE_V4 - 3 * 256;        // tid < 192
    float4 h3 = h0;
    if (has3) h3 = Ht[768 + tid];

    lds_r[tid] = r_in[bid * 256 + tid];

    float m = fmaxf(fmaxf(fmaxf(a0.x, a0.y), fmaxf(a0.z, a0.w)),
                    fmaxf(fmaxf(a1.x, a1.y), fmaxf(a1.z, a1.w)));
#pragma unroll
    for (int off = 32; off; off >>= 1) m = fmaxf(m, __shfl_xor(m, off));
    if (lane == 0) redbuf[wv] = m;
    __syncthreads();   // single barrier: covers redbuf AND lds_r
    const float inv =
        1.0f / fmaxf(fmaxf(redbuf[0], redbuf[1]), fmaxf(redbuf[2], redbuf[3]));

    f32x4* Ot = out4 + (size_t)bid * HTILE_V4;
#define EMIT(hh, qq)                                                        \
    {                                                                       \
        int q = (qq);                                                       \
        int f0 = q * 4;                                                     \
        int pl0 = f0 / LDB;                                                 \
        int rm  = f0 - pl0 * LDB;                                           \
        int pl1 = pl0 + 1; if (pl1 > 255) pl1 = 255;                        \
        float rv0 = lds_r[pl0] * inv;                                       \
        float rv1 = lds_r[pl1] * inv;                                       \
        f32x4 o;                                                            \
        o.x = (hh).x * ((rm + 0 < LDB) ? rv0 : rv1);                        \
        o.y = (hh).y * ((rm + 1 < LDB) ? rv0 : rv1);                        \
        o.z = (hh).z * ((rm + 2 < LDB) ? rv0 : rv1);                        \
        o.w = (hh).w * ((rm + 3 < LDB) ? rv0 : rv1);                        \
        __builtin_nontemporal_store(o, &Ot[q]);                             \
    }
    EMIT(h0, tid);
    EMIT(h1, 256 + tid);
    EMIT(h2, 512 + tid);
    if (has3) EMIT(h3, 768 + tid);
#undef EMIT
}

// =============== fallback path (atomic, minimal ws) ===============
__global__ __launch_bounds__(256) void pass1_atomic_k(const float* __restrict__ X,
                                                      const float* __restrict__ y,
                                                      const float* __restrict__ H,
                                                      float* __restrict__ xn_out,
                                                      unsigned int* __restrict__ gmax_atomic) {
    const int tid = threadIdx.x;
    const int p   = blockIdx.x * 256 + tid;

    const float* xp = X + (size_t)p * LL;
    const float* hp = H + (size_t)p * LDB;

    float xv[LL];
#pragma unroll
    for (int i = 0; i < LL; ++i) xv[i] = xp[i];

    float hv[LDB];
#pragma unroll
    for (int k = 0; k < LDB; ++k) hv[k] = hp[k];

    float yv = y[p];

    float s = 0.f, hmin = 1e30f, hmax = -1e30f;
#pragma unroll
    for (int k = 0; k < LDB; ++k) {
        int i0 = c_wtab.i0[k];
        float xr = 0.f;
#pragma unroll
        for (int j = 0; j < 5; ++j) {
            int i = i0 + j;
            if (i > LL - 1) i = LL - 1;
            xr += c_wtab.w[k][j] * xv[i];
        }
        float h = hv[k];
        s += h * xr;
        hmin = fminf(hmin, h);
        hmax = fmaxf(hmax, h);
    }
    float r = s - yv;

    float* op = xn_out + (size_t)p * LDB;
#pragma unroll
    for (int k = 0; k < LDB; ++k) op[k] = hv[k] * r;

    float m = (r > 0.f) ? r * hmax : r * hmin;
#pragma unroll
    for (int off = 32; off; off >>= 1) m = fmaxf(m, __shfl_xor(m, off));
    if ((tid & 63) == 0) atomicMax(gmax_atomic, enc_f32(m));
}

__global__ __launch_bounds__(256) void pass2_inplace_k(float* __restrict__ out,
                                                       const unsigned int* __restrict__ gmax) {
    float inv = 1.0f / dec_f32(*gmax);
    int idx = blockIdx.x * blockDim.x + threadIdx.x;
    if (idx >= NOUT) return;
    out[idx] *= inv;
}

extern "C" void kernel_launch(void* const* d_in, const int* in_sizes, int n_in,
                              void* d_out, int out_size, void* d_ws, size_t ws_size,
                              hipStream_t stream) {
    const float* X = (const float*)d_in[0];
    const float* y = (const float*)d_in[1];
    const float* H = (const float*)d_in[2];
    float* out = (float*)d_out;

    // ws layout: [0,256)=gmax  [256, 256+8K)=partials(2048 f)  [256+8K, ...)=r_buf
    unsigned int* gmax_u  = (unsigned int*)d_ws;
    float* partials = (float*)((char*)d_ws + 256);
    float* r_buf    = (float*)((char*)d_ws + 256 + (size_t)NPART * sizeof(float));

    const int g2s = (NOUT + 255) / 256;

    size_t need = 256 + (size_t)NPART * 4 + (size_t)NPIX * 4;
    if (ws_size >= need) {
        pass1_reg2_k<<<NBLK1, 256, 0, stream>>>(X, y, H, r_buf, partials);
        pass2_k<<<NBLK2, 256, 0, stream>>>((const float4*)H, r_buf, partials, (f32x4*)out);
    } else {
        (void)hipMemsetAsync(d_ws, 0, 256, stream);
        pass1_atomic_k<<<NBLK2, 256, 0, stream>>>(X, y, H, out, gmax_u);
        pass2_inplace_k<<<g2s, 256, 0, stream>>>(out, gmax_u);
    }
}

// Round 12
// 18.525 us; speedup vs baseline: 1.8170x; 1.8170x over previous
//
#include <hip/hip_runtime.h>
#include <hip/hip_bf16.h>

#define MM 512
#define LL 31
#define LDB 15
#define NPIX (MM*MM)
#define NOUT (NPIX*LDB)
#define NBLK1 (NPIX/256)   // 1024 pass1 blocks (256 thr)
#define NPART (NBLK1*4)    // per-wave partials: 4096 floats
#define NBLK2 (NPIX/256)   // 1024 pass2 blocks
#define HTILE_V4 (256*LDB/4)  // 960 (pass2 tile)

typedef float f32x4 __attribute__((ext_vector_type(4)));   // native vec for nt-store

// ---- compile-time resize weight table (jax.image.resize linear, antialias) ----
struct WTab { float w[LDB][5]; int i0[LDB]; };

constexpr WTab make_wtab() {
    WTab t{};
    const double inv_scale = 31.0 / 15.0;
    const double ks = inv_scale;
    for (int k = 0; k < LDB; ++k) {
        double sf = (k + 0.5) * inv_scale - 0.5;
        double wv[LL] = {};
        double wsum = 0.0;
        for (int i = 0; i < LL; ++i) {
            double d = sf - (double)i;
            if (d < 0) d = -d;
            double w = 1.0 - d / ks;
            if (w < 0) w = 0;
            wv[i] = w;
            wsum += w;
        }
        int first = 0;
        while (first < LL && wv[first] == 0.0) ++first;
        t.i0[k] = first;
        for (int j = 0; j < 5; ++j) {
            int i = first + j;
            t.w[k][j] = (i < LL) ? (float)(wv[i] / wsum) : 0.0f;
        }
    }
    return t;
}

__constant__ WTab c_wtab = make_wtab();

__device__ __forceinline__ unsigned int enc_f32(float f) {
    unsigned int b = __float_as_uint(f);
    return (b & 0x80000000u) ? ~b : (b | 0x80000000u);
}
__device__ __forceinline__ float dec_f32(unsigned int u) {
    unsigned int b = (u & 0x80000000u) ? (u & 0x7fffffffu) : ~u;
    return __uint_as_float(b);
}

// ---- pass 1 (register-direct): no LDS, no barriers ----
// Each thread loads its own contiguous X row (31 f) and H row (15 f) into
// registers. Wave footprint is one contiguous 7.9 KB region: every 128 B
// line is fetched once, later dword hits are L1. Zero sync in the kernel.
// NOTE (R9/R11 lessons): 1 px/thread @ 256-thr blocks is the occupancy
// sweet spot — bigger per-thread footprint (2px) or smaller blocks (128)
// both regressed; pass1 is latency-bound and lives on TLP.
__global__ __launch_bounds__(256) void pass1_reg_k(const float* __restrict__ X,
                                                   const float* __restrict__ y,
                                                   const float* __restrict__ H,
                                                   float* __restrict__ r_out,
                                                   float* __restrict__ partials) {
    const int tid  = threadIdx.x;
    const int bid  = blockIdx.x;
    const int lane = tid & 63;
    const int p    = bid * 256 + tid;   // grid exact: 1024*256 = NPIX

    const float* xp = X + (size_t)p * LL;
    const float* hp = H + (size_t)p * LDB;

    float xv[LL];
#pragma unroll
    for (int i = 0; i < LL; ++i) xv[i] = xp[i];

    float hv[LDB];
#pragma unroll
    for (int k = 0; k < LDB; ++k) hv[k] = hp[k];

    float yv = y[p];

    float s = 0.f, hmin = 1e30f, hmax = -1e30f;
#pragma unroll
    for (int k = 0; k < LDB; ++k) {
        int i0 = c_wtab.i0[k];
        float xr = 0.f;
#pragma unroll
        for (int j = 0; j < 5; ++j) {
            int i = i0 + j;
            if (i > LL - 1) i = LL - 1;    // weight 0 there; clamp keeps index in-bounds
            xr += c_wtab.w[k][j] * xv[i];
        }
        float h = hv[k];
        s += h * xr;
        hmin = fminf(hmin, h);
        hmax = fmaxf(hmax, h);
    }
    float r = s - yv;

    r_out[p] = r;

    // per-pixel max of H*r over k (H >= 0): r>0 ? r*hmax : r*hmin
    float m = (r > 0.f) ? r * hmax : r * hmin;
#pragma unroll
    for (int off = 32; off; off >>= 1) m = fmaxf(m, __shfl_xor(m, off));
    if (lane == 0) partials[bid * 4 + (tid >> 6)] = m;   // per-wave partial
}

// ---- pass 2: overlapped partials-reduce + out = H * r / max (1 barrier) ----
__global__ __launch_bounds__(256) void pass2_k(const float4* __restrict__ H4,
                                               const float* __restrict__ r_in,
                                               const float* __restrict__ partials,
                                               f32x4* __restrict__ out4) {
    __shared__ float lds_r[256];
    __shared__ float redbuf[4];

    const int tid  = threadIdx.x;
    const int bid  = blockIdx.x;
    const int wv   = tid >> 6;
    const int lane = tid & 63;

    // issue ALL loads up front so they overlap the reduce
    const float4* p4 = (const float4*)partials;        // NPART/4 = 1024 float4
    float4 a0 = p4[wv * 256 + lane];
    float4 a1 = p4[wv * 256 + 64 + lane];
    float4 a2 = p4[wv * 256 + 128 + lane];
    float4 a3 = p4[wv * 256 + 192 + lane];

    const float4* Ht = H4 + (size_t)bid * HTILE_V4;
    float4 h0 = Ht[tid];
    float4 h1 = Ht[256 + tid];
    float4 h2 = Ht[512 + tid];
    const bool has3 = tid < HTILE_V4 - 3 * 256;        // tid < 192
    float4 h3 = h0;
    if (has3) h3 = Ht[768 + tid];

    lds_r[tid] = r_in[bid * 256 + tid];

    float m = fmaxf(fmaxf(fmaxf(a0.x, a0.y), fmaxf(a0.z, a0.w)),
                    fmaxf(fmaxf(a1.x, a1.y), fmaxf(a1.z, a1.w)));
    m = fmaxf(m, fmaxf(fmaxf(a2.x, a2.y), fmaxf(a2.z, a2.w)));
    m = fmaxf(m, fmaxf(fmaxf(a3.x, a3.y), fmaxf(a3.z, a3.w)));
#pragma unroll
    for (int off = 32; off; off >>= 1) m = fmaxf(m, __shfl_xor(m, off));
    if (lane == 0) redbuf[wv] = m;
    __syncthreads();   // single barrier: covers redbuf AND lds_r
    const float inv =
        1.0f / fmaxf(fmaxf(redbuf[0], redbuf[1]), fmaxf(redbuf[2], redbuf[3]));

    f32x4* Ot = out4 + (size_t)bid * HTILE_V4;
#define EMIT(hh, qq)                                                        \
    {                                                                       \
        int q = (qq);                                                       \
        int f0 = q * 4;                                                     \
        int pl0 = f0 / LDB;                                                 \
        int rm  = f0 - pl0 * LDB;                                           \
        int pl1 = pl0 + 1; if (pl1 > 255) pl1 = 255;                        \
        float rv0 = lds_r[pl0] * inv;                                       \
        float rv1 = lds_r[pl1] * inv;                                       \
        f32x4 o;                                                            \
        o.x = (hh).x * ((rm + 0 < LDB) ? rv0 : rv1);                        \
        o.y = (hh).y * ((rm + 1 < LDB) ? rv0 : rv1);                        \
        o.z = (hh).z * ((rm + 2 < LDB) ? rv0 : rv1);                        \
        o.w = (hh).w * ((rm + 3 < LDB) ? rv0 : rv1);                        \
        __builtin_nontemporal_store(o, &Ot[q]);                             \
    }
    EMIT(h0, tid);
    EMIT(h1, 256 + tid);
    EMIT(h2, 512 + tid);
    if (has3) EMIT(h3, 768 + tid);
#undef EMIT
}

// =============== fallback path (atomic, minimal ws) ===============
__global__ __launch_bounds__(256) void pass1_atomic_k(const float* __restrict__ X,
                                                      const float* __restrict__ y,
                                                      const float* __restrict__ H,
                                                      float* __restrict__ xn_out,
                                                      unsigned int* __restrict__ gmax_atomic) {
    const int tid = threadIdx.x;
    const int p   = blockIdx.x * 256 + tid;

    const float* xp = X + (size_t)p * LL;
    const float* hp = H + (size_t)p * LDB;

    float xv[LL];
#pragma unroll
    for (int i = 0; i < LL; ++i) xv[i] = xp[i];

    float hv[LDB];
#pragma unroll
    for (int k = 0; k < LDB; ++k) hv[k] = hp[k];

    float yv = y[p];

    float s = 0.f, hmin = 1e30f, hmax = -1e30f;
#pragma unroll
    for (int k = 0; k < LDB; ++k) {
        int i0 = c_wtab.i0[k];
        float xr = 0.f;
#pragma unroll
        for (int j = 0; j < 5; ++j) {
            int i = i0 + j;
            if (i > LL - 1) i = LL - 1;
            xr += c_wtab.w[k][j] * xv[i];
        }
        float h = hv[k];
        s += h * xr;
        hmin = fminf(hmin, h);
        hmax = fmaxf(hmax, h);
    }
    float r = s - yv;

    float* op = xn_out + (size_t)p * LDB;
#pragma unroll
    for (int k = 0; k < LDB; ++k) op[k] = hv[k] * r;

    float m = (r > 0.f) ? r * hmax : r * hmin;
#pragma unroll
    for (int off = 32; off; off >>= 1) m = fmaxf(m, __shfl_xor(m, off));
    if ((tid & 63) == 0) atomicMax(gmax_atomic, enc_f32(m));
}

__global__ __launch_bounds__(256) void pass2_inplace_k(float* __restrict__ out,
                                                       const unsigned int* __restrict__ gmax) {
    float inv = 1.0f / dec_f32(*gmax);
    int idx = blockIdx.x * blockDim.x + threadIdx.x;
    if (idx >= NOUT) return;
    out[idx] *= inv;
}

extern "C" void kernel_launch(void* const* d_in, const int* in_sizes, int n_in,
                              void* d_out, int out_size, void* d_ws, size_t ws_size,
                              hipStream_t stream) {
    const float* X = (const float*)d_in[0];
    const float* y = (const float*)d_in[1];
    const float* H = (const float*)d_in[2];
    float* out = (float*)d_out;

    // ws layout: [0,256)=gmax  [256, 256+16K)=partials(4096 f)  [256+16K, ...)=r_buf
    unsigned int* gmax_u  = (unsigned int*)d_ws;
    float* partials = (float*)((char*)d_ws + 256);
    float* r_buf    = (float*)((char*)d_ws + 256 + (size_t)NPART * sizeof(float));

    const int g2s = (NOUT + 255) / 256;

    size_t need = 256 + (size_t)NPART * 4 + (size_t)NPIX * 4;
    if (ws_size >= need) {
        pass1_reg_k<<<NBLK1, 256, 0, stream>>>(X, y, H, r_buf, partials);
        pass2_k<<<NBLK2, 256, 0, stream>>>((const float4*)H, r_buf, partials, (f32x4*)out);
    } else {
        (void)hipMemsetAsync(d_ws, 0, 256, stream);
        pass1_atomic_k<<<NBLK2, 256, 0, stream>>>(X, y, H, out, gmax_u);
        pass2_inplace_k<<<g2s, 256, 0, stream>>>(out, gmax_u);
    }
}